// Round 6
// baseline (58.550 us; speedup 1.0000x reference)
//
#include <hip/hip_runtime.h>
#include <hip/hip_bf16.h>

#define NCLASS 19
#define BINS 512
#define NB (NCLASS * BINS)  // 9728 bins
#define NREP 2
#define RPAD 8              // words; shifts replica 1's bank phase by 8 banks
#define RSTRIDE (NB + RPAD)
#define SLICES 8
#define IGNORE_IDX (-100)
#define HW_SHIFT 18  // 512*512 = 2^18 (fixed problem shape)
#define HW_C (1 << HW_SHIFT)

// ---------------------------------------------------------------------------
// Phase 1: 1 px/thread scalar loads; per-pixel softmax over 19 classes;
// 2-way lane-replicated LDS histogram (u32-packed pos<<16|neg), 39 KB/block
// so TWO 1024-thread blocks fit per CU -> 32 waves/CU (max) to hide the
// 19-stream global-load latency. __launch_bounds__(1024,8) caps VGPR at 64
// (live set ~35, no spill). ppb = 4096 keeps u16 fields overflow-free.
// ---------------------------------------------------------------------------
__global__ void __launch_bounds__(1024, 8) hist_occ(
    const float* __restrict__ logits, const int* __restrict__ labels,
    unsigned* __restrict__ copies, int P, int ppb) {
  extern __shared__ unsigned sh[];  // NREP*RSTRIDE words = 39 KB
  for (int i = threadIdx.x; i < NREP * RSTRIDE; i += 1024) sh[i] = 0u;
  __syncthreads();

  const int rep = (threadIdx.x & 1) * RSTRIDE;

  int p0 = blockIdx.x * ppb;
  int p1 = min(P, p0 + ppb);
  for (int p = p0 + (int)threadIdx.x; p < p1; p += 1024) {
    int n = p >> HW_SHIFT;
    int hw = p & (HW_C - 1);
    const float* lp = logits + (((size_t)n * NCLASS) << HW_SHIFT) + hw;

    float v[NCLASS];
    float m = -3.4e38f;
#pragma unroll
    for (int c = 0; c < NCLASS; ++c) {
      v[c] = lp[(size_t)c << HW_SHIFT];
      m = fmaxf(m, v[c]);
    }
    float s = 0.f;
#pragma unroll
    for (int c = 0; c < NCLASS; ++c) {
      v[c] = __expf(v[c] - m);
      s += v[c];
    }
    float inv = 1.0f / s;

    int lb = labels[p];
    if (lb == IGNORE_IDX) continue;

#pragma unroll
    for (int c = 0; c < NCLASS; ++c) {
      float prob = v[c] * inv;
      bool pos = (c == lb);
      float e = pos ? (1.0f - prob) : prob;
      int b = min(BINS - 1, (int)(e * (float)BINS));
      atomicAdd(&sh[rep + (c << 9) + b], pos ? 0x10000u : 1u);
    }
  }
  __syncthreads();

  unsigned* dst = copies + (size_t)blockIdx.x * NB;
  for (int i = threadIdx.x; i < NB; i += 1024) dst[i] = sh[i] + sh[RSTRIDE + i];
}

// ---------------------------------------------------------------------------
// Phase 2: partial tree-reduce of the R copies. Slice s sums copies r==s
// (mod SLICES) into u64 packed (pos<<32 | neg). Coalesced, no atomics.
// ---------------------------------------------------------------------------
__global__ void __launch_bounds__(256) reduce_part(
    const unsigned* __restrict__ copies, unsigned long long* __restrict__ part,
    int R) {
  const int nblk = NB / 256;  // 38
  int s = blockIdx.x / nblk;
  int blk = blockIdx.x - s * nblk;
  int cb = blk * 256 + threadIdx.x;
  unsigned long long acc = 0;
  for (int r = s; r < R; r += SLICES) {
    unsigned v = copies[(size_t)r * NB + cb];
    acc += ((unsigned long long)(v >> 16) << 32) |
           (unsigned long long)(v & 0xffffu);
  }
  part[(size_t)s * NB + cb] = acc;
}

// ---------------------------------------------------------------------------
// Phase 3: fold the SLICES partials per class, then suffix scan over bins and
// Lovasz J accumulation. loss_c = (1/BINS) * sum_{b>=1} J_b, with (CP,CN)
// the inclusive suffix counts at bin b.
// ---------------------------------------------------------------------------
__global__ void __launch_bounds__(256) scan19_fold(
    const unsigned long long* __restrict__ part, float* __restrict__ partial) {
  int c = blockIdx.x;
  __shared__ unsigned long long bins[BINS];
  __shared__ unsigned long long arr[256];
  __shared__ unsigned long long wsum[4];
  __shared__ float fsum[4];
  int tid = threadIdx.x;

  for (int i = tid; i < BINS; i += 256) {
    unsigned long long a = 0;
#pragma unroll
    for (int s = 0; s < SLICES; ++s) a += part[(size_t)s * NB + c * BINS + i];
    bins[i] = a;
  }
  __syncthreads();

  // class total (for nPos)
  unsigned long long t = 0;
  for (int i = tid; i < BINS; i += 256) t += bins[i];
  for (int off = 32; off > 0; off >>= 1) t += __shfl_down(t, off, 64);
  int lane = tid & 63, w = tid >> 6;
  if (lane == 0) wsum[w] = t;
  __syncthreads();
  unsigned long long total = wsum[0] + wsum[1] + wsum[2] + wsum[3];
  float nPos = (float)(unsigned)(total >> 32);

  // suffix scan, 256-bin rows from the top, carry in `above`
  unsigned long long above = 0;
  float acc = 0.f;
  for (int r = BINS / 256 - 1; r >= 0; --r) {
    arr[tid] = bins[r * 256 + tid];
    __syncthreads();
    for (int off = 1; off < 256; off <<= 1) {
      unsigned long long add = (tid + off < 256) ? arr[tid + off] : 0ull;
      __syncthreads();
      arr[tid] += add;
      __syncthreads();
    }
    unsigned long long suff = arr[tid] + above;
    unsigned long long rowTot = arr[0];
    __syncthreads();

    int gb = r * 256 + tid;
    if (gb >= 1) {
      float CP = (float)(unsigned)(suff >> 32);
      float CN = (float)(unsigned)(suff & 0xffffffffull);
      float uni = nPos + CN;
      if (uni > 0.f) acc += 1.0f - (nPos - CP) / uni;
    }
    above += rowTot;
  }

  for (int off = 32; off > 0; off >>= 1) acc += __shfl_down(acc, off, 64);
  if (lane == 0) fsum[w] = acc;
  __syncthreads();
  if (tid == 0) partial[c] = fsum[0] + fsum[1] + fsum[2] + fsum[3];
}

// ---------------------------------------------------------------------------
// Phase 4: mean over classes (fixed-order, deterministic).
// ---------------------------------------------------------------------------
__global__ void __launch_bounds__(64) lovasz_final(
    const float* __restrict__ partial, float* __restrict__ out, int n,
    float scale) {
  float acc = 0.f;
  for (int i = threadIdx.x; i < n; i += 64) acc += partial[i];
  for (int off = 32; off > 0; off >>= 1) acc += __shfl_down(acc, off, 64);
  if (threadIdx.x == 0) out[0] = acc * scale;
}

extern "C" void kernel_launch(void* const* d_in, const int* in_sizes, int n_in,
                              void* d_out, int out_size, void* d_ws,
                              size_t ws_size, hipStream_t stream) {
  const float* logits = (const float*)d_in[0];
  const int* labels = (const int*)d_in[1];
  float* out = (float*)d_out;

  const int P = in_sizes[1];  // 8*512*512 = 2,097,152

  // R = copy count = grid size; 512 -> 2 blocks/CU. Shrink if ws is tiny.
  int R = 512;
  while (R > 32 &&
         (size_t)R * NB * 4 + (size_t)SLICES * NB * 8 + 4096 > ws_size)
    R >>= 1;
  int ppb = (P + R - 1) / R;  // 4096 at R=512 — u16-safe

  char* ws = (char*)d_ws;
  unsigned* copies = (unsigned*)ws;
  unsigned long long* part = (unsigned long long*)(ws + (size_t)R * NB * 4);
  float* partial = (float*)(part + (size_t)SLICES * NB);

  size_t ldsBytes = (size_t)NREP * RSTRIDE * 4;  // ~39 KB -> 2 blocks/CU

  hist_occ<<<R, 1024, ldsBytes, stream>>>(logits, labels, copies, P, ppb);
  reduce_part<<<SLICES * (NB / 256), 256, 0, stream>>>(copies, part, R);
  scan19_fold<<<NCLASS, 256, 0, stream>>>(part, partial);
  lovasz_final<<<1, 64, 0, stream>>>(partial, out, NCLASS,
                                     1.0f / ((float)BINS * (float)NCLASS));
}